// Round 1
// 249.628 us; speedup vs baseline: 1.0023x; 1.0023x over previous
//
#include <hip/hip_runtime.h>
#include <hip/hip_bf16.h>
#include <stdint.h>

// ---------------------------------------------------------------------------
// Single-head self-attention, B=4, S=2048, D=1024, fp32 in/out.
// Round 9: k_qkv/k_pv/k_prep unchanged (qkv is at the 2ph K=1024 ceiling,
// 652 TF == m248's 655; its 384-block 256^2 packing would eat the 8ph gain).
// NEW k_score: 256^2 tile, 512 thr (8 waves of 128x64), BK=64, 8-phase
// schedule with counted vmcnt(4) (never drains to 0 in steady state),
// XOR-swizzled LDS (16-way -> 2-way bank conflict on ds_read_b128),
// s_setprio around each 16-MFMA cluster. Grid 256 = exactly 1 block/CU.
// Pipeline (4 dispatches):
//   1. k_prep:  xb=bf16(x); wt=bf16(W^T); rowsum=0
//   2. k_qkv:   q,k = x@W+b (bf16); v -> vT transposed  [XCD-swizzled]
//   3. k_score: P' = exp2(q@k^T*s*log2e) (bf16) + rowsum atomics [8-phase]
//   4. k_pv:    out = (P' @ vT^T)/rowsum (fp32 -> d_out)
// ---------------------------------------------------------------------------

typedef __attribute__((ext_vector_type(8))) short short8;   // 8 bf16 = 4 VGPR
typedef __attribute__((ext_vector_type(4))) float f32x4;    // MFMA C/D

__device__ __forceinline__ unsigned short f2bf(float f) {
  union { float f; uint32_t u; } c; c.f = f;
  uint32_t u = c.u;
  u += 0x7FFFu + ((u >> 16) & 1u);   // RNE
  return (unsigned short)(u >> 16);
}

// async global->LDS, 16B/lane; LDS dest is wave-uniform base + lane*16.
__device__ __forceinline__ void gl16(const void* g, void* l) {
  __builtin_amdgcn_global_load_lds(
      (const __attribute__((address_space(1))) unsigned int*)g,
      (__attribute__((address_space(3))) unsigned int*)l, 16, 0, 0);
}

#define FENCE() asm volatile("" ::: "memory")
#define BARRIER() do { FENCE(); __builtin_amdgcn_s_barrier(); FENCE(); } while (0)
#define VMWAIT(n) asm volatile("s_waitcnt vmcnt(" #n ")" ::: "memory")

// ----------------- k_qkv: 128x128, 256 thr, fused vT, XCD map (round 4) ----
__global__ __launch_bounds__(256) void k_qkv(
    const short* __restrict__ A, const short* __restrict__ B,
    short* __restrict__ Cb, short* __restrict__ vT,
    const float* __restrict__ b0, const float* __restrict__ b1,
    const float* __restrict__ b2)
{
  // 1536 blocks: xcd(b&7) owns tileM rows xcd*8.. for ALL z (A-slab shared)
  const int b = blockIdx.x;
  const int xcd = b & 7, r = b >> 3;
  const int z = r >> 6;
  const int mem = r & 63;
  const int tm = xcd * 8 + (mem >> 3);
  const int tn = mem & 7;

  __shared__ short lds[18432];   // 2 bufs x (sA 4096 | sB 4096); overlay 4x4608

  const int tid  = threadIdx.x;
  const int lane = tid & 63;
  const int wid  = tid >> 6;
  const long tileM = (long)tm * 128;
  const long tileN = (long)tn * 128;
  const short* Az = A;
  const short* Bz = B + (long)z * 1048576L;

  const int c0 = tid, c1 = 256 + tid;
  const short* gA0 = Az + (tileM + (c0 >> 2)) * 1024 + (c0 & 3) * 8;
  const short* gA1 = Az + (tileM + (c1 >> 2)) * 1024 + (c1 & 3) * 8;
  const short* gB0 = Bz + (tileN + (c0 >> 2)) * 1024 + (c0 & 3) * 8;
  const short* gB1 = Bz + (tileN + (c1 >> 2)) * 1024 + (c1 & 3) * 8;

  const int fr = lane & 15, quad = lane >> 4;
  const int waveM = (wid >> 1) * 64, waveN = (wid & 1) * 64;

  f32x4 acc[4][4] = {};

  {
    short* base = lds;
    gl16(gA0, base + c0 * 8);
    gl16(gA1, base + c1 * 8);
    gl16(gB0, base + 4096 + c0 * 8);
    gl16(gB1, base + 4096 + c1 * 8);
  }

  for (int t = 0; t < 32; ++t) {
    __syncthreads();
    if (t + 1 < 32) {
      const int kt = (t + 1) << 5;
      short* base = lds + ((t + 1) & 1) * 8192;
      gl16(gA0 + kt, base + c0 * 8);
      gl16(gA1 + kt, base + c1 * 8);
      gl16(gB0 + kt, base + 4096 + c0 * 8);
      gl16(gB1 + kt, base + 4096 + c1 * 8);
    }
    const short* sA = lds + (t & 1) * 8192;
    const short* sB = sA + 4096;
    short8 af[4], bf[4];
#pragma unroll
    for (int i = 0; i < 4; ++i)
      af[i] = *(const short8*)&sA[(waveM + i * 16 + fr) * 32 + quad * 8];
#pragma unroll
    for (int j = 0; j < 4; ++j)
      bf[j] = *(const short8*)&sB[(waveN + j * 16 + fr) * 32 + quad * 8];
#pragma unroll
    for (int i = 0; i < 4; ++i)
#pragma unroll
      for (int j = 0; j < 4; ++j)
        acc[i][j] = __builtin_amdgcn_mfma_f32_16x16x32_bf16(af[i], bf[j],
                                                            acc[i][j], 0, 0, 0);
  }

  // C/D layout: row=(lane>>4)*4+r, col=lane&15 (m89/m91-verified).
  if (z == 2) {
    // v-tile: add bias, write TRANSPOSED scratch [d][t], store vT[b][d][t]
    __syncthreads();
    short* scr = lds + wid * 4608;   // [64][72]
#pragma unroll
    for (int j = 0; j < 4; ++j) {
      const float bv = b2[tileN + waveN + j * 16 + fr];
#pragma unroll
      for (int i = 0; i < 4; ++i)
#pragma unroll
        for (int r = 0; r < 4; ++r)
          scr[(j * 16 + fr) * 72 + i * 16 + quad * 4 + r] =
              (short)f2bf(acc[i][j][r] + bv);
    }
    const int gb = tm >> 4;
    const long t0 = (long)(tm & 15) * 128 + waveM;
#pragma unroll
    for (int c = 0; c < 8; ++c) {
      const int rr = c * 8 + (lane >> 3);
      const int cc = (lane & 7) * 8;
      short8 v = *(const short8*)&scr[rr * 72 + cc];
      const long gd = tileN + waveN + rr;
      *(short8*)(vT + ((long)gb << 21) + gd * 2048 + t0 + cc) = v;
    }
  } else {
    __syncthreads();
    short* scr = lds + wid * 4608;   // [64][72]
    short* C = Cb + (long)z * 8388608L;
    const float* bias = (z == 0) ? b0 : b1;
#pragma unroll
    for (int j = 0; j < 4; ++j) {
      const float bv = bias[tileN + waveN + j * 16 + fr];
#pragma unroll
      for (int i = 0; i < 4; ++i)
#pragma unroll
        for (int r = 0; r < 4; ++r)
          scr[(i * 16 + quad * 4 + r) * 72 + j * 16 + fr] =
              (short)f2bf(acc[i][j][r] + bv);
    }
#pragma unroll
    for (int c = 0; c < 8; ++c) {
      const int row = c * 8 + (lane >> 3);
      const int col = (lane & 7) * 8;
      short8 v = *(const short8*)&scr[row * 72 + col];
      *(short8*)(C + (tileM + waveM + row) * 1024 + tileN + waveN + col) = v;
    }
  }
}

// ---------------- k_score: 256x256 tile, 512 thr, 8-phase pipeline ---------
// P' = exp2(q@k^T * scale) bf16 + rowsum atomics. K=1024, BK=64.
// LDS 128KB: 2 bufs x (A 256x64 | B 256x64) bf16, each tile stored as two
// 128-row halves, 16B chunks XOR-swizzled: chunk c holds global
// (row=c>>3, slot=(c&7)^(row&7)); fragment reads apply the same involution,
// turning the 16-way ds_read_b128 conflict into a free 2-way.
// Stage pattern per tile t: P0/P1 -> B halves of t+1 (2+2), P3 -> A of t+2
// (4). vmcnt(4) at each tile boundary keeps A(t+2) in flight (T4).
// Grid 256 blocks (1/CU): xcd=b&7 keeps all 8 tn-tiles of one A-slab on
// one XCD for L2 reuse.
__global__ __launch_bounds__(512, 2) void k_score(
    const short* __restrict__ A, const short* __restrict__ B,
    short* __restrict__ Pp, float scale, float* __restrict__ rowsum)
{
  __shared__ short lds[65536];   // 128 KB

  const int b = blockIdx.x;
  const int xcd = b & 7, jb = b >> 3;
  const int p = xcd * 4 + (jb >> 3);   // 32 (z,tm) slabs, 4 per XCD
  const int tn = jb & 7;
  const int z = p >> 3, tm = p & 7;

  const int tid = threadIdx.x;
  const int lane = tid & 63;
  const int wid = tid >> 6;            // 0..7
  const int fr = lane & 15, quad = lane >> 4;
  const int wm = wid >> 2, wn = wid & 3;   // wave owns rows wm*128.., cols wn*64..

  const long tileM = (long)tm * 256;
  const long tileN = (long)tn * 256;
  const short* Az = A + (long)z * 2097152L;
  const short* Bz = B + (long)z * 2097152L;

  // staging: chunk c=tid -> (row=c>>3, swizzled slot) of half 0; chunk c+512
  // is +64 rows (same slot: (row+64)&7 == row&7).
  const int srow = tid >> 3;
  const int sslot = (tid & 7) ^ (srow & 7);
  const short* gA = Az + (tileM + srow) * 1024 + sslot * 8;
  const short* gB = Bz + (tileN + srow) * 1024 + sslot * 8;

  // fragment read offsets (shorts); row&7 == fr&7 since 16|row-block
  const int frk = fr & 7;
  const int aBase = wm << 13;                                 // own A half
  const int bRow  = 16384 + ((wn >> 1) << 13) + ((wn & 1) << 12); // own B half+64
  const int o0 = ((quad ^ frk) << 3) + (fr << 6);             // kk=0 slot
  const int o1 = (((quad + 4) ^ frk) << 3) + (fr << 6);       // kk=1 slot

  f32x4 acc[8][4] = {};

  auto stageA = [&](int tt) {          // 4 loads: both halves of A tile tt
    const short* s = gA + tt * 64;
    short* d = &lds[(tt & 1) << 15];
    gl16(s,          d + (tid << 3));
    gl16(s + 65536,  d + 4096 + (tid << 3));
    gl16(s + 131072, d + 8192 + (tid << 3));
    gl16(s + 196608, d + 12288 + (tid << 3));
  };
  auto stageBh = [&](int tt, int h) {  // 2 loads: B half h of tile tt
    const short* s = gB + tt * 64 + h * 131072;
    short* d = &lds[((tt & 1) << 15) + 16384 + (h << 13)];
    gl16(s,         d + (tid << 3));
    gl16(s + 65536, d + 4096 + (tid << 3));
  };

  // prologue: A0(4) B0(4) A1(4); drain oldest 8, keep A1 in flight
  stageA(0); stageBh(0, 0); stageBh(0, 1); stageA(1);
  VMWAIT(4);
  BARRIER();

#pragma unroll 1
  for (int t = 0; t < 16; ++t) {
    const int bb = (t & 1) << 15;
    short8 af0[4][2], af1[4][2], bf0[2][2], bf1[2][2];

    // ---- phase 0: quadrant rows 0-63 x cols 0-31 (of wave tile)
#pragma unroll
    for (int i = 0; i < 4; ++i) {
      af0[i][0] = *(const short8*)&lds[bb + aBase + (i << 10) + o0];
      af0[i][1] = *(const short8*)&lds[bb + aBase + (i << 10) + o1];
    }
#pragma unroll
    for (int j = 0; j < 2; ++j) {
      bf0[j][0] = *(const short8*)&lds[bb + bRow + (j << 10) + o0];
      bf0[j][1] = *(const short8*)&lds[bb + bRow + (j << 10) + o1];
    }
    if (t + 1 < 16) stageBh(t + 1, 0);
    BARRIER();
    __builtin_amdgcn_s_setprio(1);
#pragma unroll
    for (int i = 0; i < 4; ++i)
#pragma unroll
      for (int j = 0; j < 2; ++j) {
        acc[i][j] = __builtin_amdgcn_mfma_f32_16x16x32_bf16(af0[i][0], bf0[j][0], acc[i][j], 0, 0, 0);
        acc[i][j] = __builtin_amdgcn_mfma_f32_16x16x32_bf16(af0[i][1], bf0[j][1], acc[i][j], 0, 0, 0);
      }
    __builtin_amdgcn_s_setprio(0);
    BARRIER();

    // ---- phase 1: rows 64-127 x cols 0-31
#pragma unroll
    for (int i = 0; i < 4; ++i) {
      af1[i][0] = *(const short8*)&lds[bb + aBase + ((i + 4) << 10) + o0];
      af1[i][1] = *(const short8*)&lds[bb + aBase + ((i + 4) << 10) + o1];
    }
    if (t + 1 < 16) stageBh(t + 1, 1);
    BARRIER();
    __builtin_amdgcn_s_setprio(1);
#pragma unroll
    for (int i = 0; i < 4; ++i)
#pragma unroll
      for (int j = 0; j < 2; ++j) {
        acc[i + 4][j] = __builtin_amdgcn_mfma_f32_16x16x32_bf16(af1[i][0], bf0[j][0], acc[i + 4][j], 0, 0, 0);
        acc[i + 4][j] = __builtin_amdgcn_mfma_f32_16x16x32_bf16(af1[i][1], bf0[j][1], acc[i + 4][j], 0, 0, 0);
      }
    __builtin_amdgcn_s_setprio(0);
    BARRIER();

    // ---- phase 2: rows 64-127 x cols 32-63
#pragma unroll
    for (int j = 0; j < 2; ++j) {
      bf1[j][0] = *(const short8*)&lds[bb + bRow + ((j + 2) << 10) + o0];
      bf1[j][1] = *(const short8*)&lds[bb + bRow + ((j + 2) << 10) + o1];
    }
    BARRIER();
    __builtin_amdgcn_s_setprio(1);
#pragma unroll
    for (int i = 0; i < 4; ++i)
#pragma unroll
      for (int j = 0; j < 2; ++j) {
        acc[i + 4][j + 2] = __builtin_amdgcn_mfma_f32_16x16x32_bf16(af1[i][0], bf1[j][0], acc[i + 4][j + 2], 0, 0, 0);
        acc[i + 4][j + 2] = __builtin_amdgcn_mfma_f32_16x16x32_bf16(af1[i][1], bf1[j][1], acc[i + 4][j + 2], 0, 0, 0);
      }
    __builtin_amdgcn_s_setprio(0);
    BARRIER();

    // ---- phase 3: rows 0-63 x cols 32-63; stage A(t+2) after its region's
    // reads are chip-wide complete (all waves past phase-1's end barrier).
    if (t + 2 < 16) stageA(t + 2);
    BARRIER();
    __builtin_amdgcn_s_setprio(1);
#pragma unroll
    for (int i = 0; i < 4; ++i)
#pragma unroll
      for (int j = 0; j < 2; ++j) {
        acc[i][j + 2] = __builtin_amdgcn_mfma_f32_16x16x32_bf16(af0[i][0], bf1[j][0], acc[i][j + 2], 0, 0, 0);
        acc[i][j + 2] = __builtin_amdgcn_mfma_f32_16x16x32_bf16(af0[i][1], bf1[j][1], acc[i][j + 2], 0, 0, 0);
      }
    __builtin_amdgcn_s_setprio(0);
    // tile boundary: drain A(t+1)+B(t+1), keep A(t+2) in flight (4 loads);
    // t=14: A(16) not issued, so drain fully to cover B(15).
    if (t < 14) { VMWAIT(4); } else { VMWAIT(0); }
    BARRIER();
  }

  // exp2 (register-only, overlaps nothing in LDS)
#pragma unroll
  for (int i = 0; i < 8; ++i)
#pragma unroll
    for (int j = 0; j < 4; ++j)
#pragma unroll
      for (int r = 0; r < 4; ++r)
        acc[i][j][r] = exp2f(acc[i][j][r] * scale);

  // rowsum partials: row = wm*128 + i*16 + quad*4 + r; cols spread over fr+j
  float* rsz = rowsum + (long)z * 2048 + tileM + wm * 128;
#pragma unroll
  for (int i = 0; i < 8; ++i)
#pragma unroll
    for (int r = 0; r < 4; ++r) {
      float s = acc[i][0][r] + acc[i][1][r] + acc[i][2][r] + acc[i][3][r];
      s += __shfl_xor(s, 1);
      s += __shfl_xor(s, 2);
      s += __shfl_xor(s, 4);
      s += __shfl_xor(s, 8);
      if (fr == 0) atomicAdd(&rsz[i * 16 + quad * 4 + r], s);
    }

  // bf16 store via per-wave LDS transpose scratch (overlays staging bufs;
  // all staging loads retired and all reads done -> one full barrier).
  __syncthreads();
  short* C = Pp + (long)z * 4194304L;
  short* scr = &lds[wid * 4608];   // [64][72] per wave
#pragma unroll
  for (int pass = 0; pass < 2; ++pass) {
#pragma unroll
    for (int j = 0; j < 4; ++j)
#pragma unroll
      for (int i = 0; i < 4; ++i)
#pragma unroll
        for (int r = 0; r < 4; ++r)
          scr[(i * 16 + quad * 4 + r) * 72 + j * 16 + fr] =
              (short)f2bf(acc[pass * 4 + i][j][r]);
    // same-wave ds_write->ds_read (and pass-1 WAR) ordered via lgkmcnt
#pragma unroll
    for (int c = 0; c < 8; ++c) {
      const int row = c * 8 + (lane >> 3);
      const int col = (lane & 7) * 8;
      short8 v = *(const short8*)&scr[row * 72 + col];
      *(short8*)(C + (tileM + wm * 128 + pass * 64 + row) * 2048 +
                 tileN + wn * 64 + col) = v;
    }
  }
}

// ----------------- k_pv: 128x128, 256 thr, swizzled (round 4) --------------
// out = (P' @ vT^T) / rowsum, fp32. K=2048, BK=32 dbuf. Grid 512.
__global__ __launch_bounds__(256) void k_pv(
    const short* __restrict__ A, const short* __restrict__ B,
    float* __restrict__ Cf, float* __restrict__ rowsum)
{
  const int b = blockIdx.x;
  const int s = b & 7, r0_ = b >> 3;
  const int z = r0_ >> 4;
  const int mem = r0_ & 15;
  const int tm = (s >> 1) * 4 + (mem >> 2);
  const int tn = (s & 1) * 4 + (mem & 3);

  __shared__ short lds[18432];

  const int tid  = threadIdx.x;
  const int lane = tid & 63;
  const int wid  = tid >> 6;
  const long tileM = (long)tm * 128;
  const long tileN = (long)tn * 128;
  const short* Az = A + (long)z * 4194304L;
  const short* Bz = B + (long)z * 2097152L;

  const int c0 = tid, c1 = 256 + tid;
  const short* gA0 = Az + (tileM + (c0 >> 2)) * 2048 + (c0 & 3) * 8;
  const short* gA1 = Az + (tileM + (c1 >> 2)) * 2048 + (c1 & 3) * 8;
  const short* gB0 = Bz + (tileN + (c0 >> 2)) * 2048 + (c0 & 3) * 8;
  const short* gB1 = Bz + (tileN + (c1 >> 2)) * 2048 + (c1 & 3) * 8;

  const int fr = lane & 15, quad = lane >> 4;
  const int waveM = (wid >> 1) * 64, waveN = (wid & 1) * 64;

  f32x4 acc[4][4] = {};

  {
    short* base = lds;
    gl16(gA0, base + c0 * 8);
    gl16(gA1, base + c1 * 8);
    gl16(gB0, base + 4096 + c0 * 8);
    gl16(gB1, base + 4096 + c1 * 8);
  }

  for (int t = 0; t < 64; ++t) {
    __syncthreads();
    if (t + 1 < 64) {
      const int kt = (t + 1) << 5;
      short* base = lds + ((t + 1) & 1) * 8192;
      gl16(gA0 + kt, base + c0 * 8);
      gl16(gA1 + kt, base + c1 * 8);
      gl16(gB0 + kt, base + 4096 + c0 * 8);
      gl16(gB1 + kt, base + 4096 + c1 * 8);
    }
    const short* sA = lds + (t & 1) * 8192;
    const short* sB = sA + 4096;
    short8 af[4], bf[4];
#pragma unroll
    for (int i = 0; i < 4; ++i)
      af[i] = *(const short8*)&sA[(waveM + i * 16 + fr) * 32 + quad * 8];
#pragma unroll
    for (int j = 0; j < 4; ++j)
      bf[j] = *(const short8*)&sB[(waveN + j * 16 + fr) * 32 + quad * 8];
#pragma unroll
    for (int i = 0; i < 4; ++i)
#pragma unroll
      for (int j = 0; j < 4; ++j)
        acc[i][j] = __builtin_amdgcn_mfma_f32_16x16x32_bf16(af[i], bf[j],
                                                            acc[i][j], 0, 0, 0);
  }

  float* C = Cf + (long)z * 2097152L;
#pragma unroll
  for (int i = 0; i < 4; ++i)
#pragma unroll
    for (int r = 0; r < 4; ++r) {
      const long gr = tileM + waveM + i * 16 + quad * 4 + r;
      const float rinv = 1.0f / rowsum[(long)z * 2048 + gr];
#pragma unroll
      for (int j = 0; j < 4; ++j)
        C[gr * 1024 + tileN + waveN + j * 16 + fr] = acc[i][j][r] * rinv;
    }
}

// prep: blocks [0,8192) cvt x -> bf16; [8192,11264) W^T -> bf16; 11264 zero rs
__global__ __launch_bounds__(256) void k_prep(
    const float4* __restrict__ x, ushort4* __restrict__ xb,
    const float* __restrict__ Wq, const float* __restrict__ Wk,
    const float* __restrict__ Wv, short* __restrict__ WT,
    float* __restrict__ rs)
{
  __shared__ short tile[32][33];
  const int b = blockIdx.x;
  if (b < 8192) {
    const long i = (long)b * 256 + threadIdx.x;
    float4 v = x[i];
    ushort4 o;
    o.x = f2bf(v.x); o.y = f2bf(v.y); o.z = f2bf(v.z); o.w = f2bf(v.w);
    xb[i] = o;
  } else if (b < 11264) {
    const int idx = b - 8192;
    const int z = idx >> 10, rem = idx & 1023;
    const float* W = (z == 0) ? Wq : ((z == 1) ? Wk : Wv);
    short* d = WT + (long)z * 1024 * 1024;
    const int n0 = (rem & 31) * 32, d0 = (rem >> 5) * 32;
    const int tx = threadIdx.x & 31, ty = threadIdx.x >> 5;
#pragma unroll
    for (int p = 0; p < 4; ++p)
      tile[ty + p * 8][tx] = (short)f2bf(W[(long)(d0 + ty + p * 8) * 1024 + n0 + tx]);
    __syncthreads();
#pragma unroll
    for (int p = 0; p < 4; ++p)
      d[(long)(n0 + ty + p * 8) * 1024 + d0 + tx] = tile[tx][ty + p * 8];
  } else {
#pragma unroll
    for (int p = 0; p < 32; ++p)
      rs[p * 256 + threadIdx.x] = 0.0f;
  }
}

extern "C" void kernel_launch(void* const* d_in, const int* in_sizes, int n_in,
                              void* d_out, int out_size, void* d_ws, size_t ws_size,
                              hipStream_t stream) {
  const float* x  = (const float*)d_in[0];
  const float* Wq = (const float*)d_in[1];
  const float* bq = (const float*)d_in[2];
  const float* Wk = (const float*)d_in[3];
  const float* bk = (const float*)d_in[4];
  const float* Wv = (const float*)d_in[5];
  const float* bv = (const float*)d_in[6];

  char* ws = (char*)d_ws;
  short* xb  = (short*)(ws);                  // 16 MB
  short* wt  = (short*)(ws + 16777216);       // 6 MB
  short* qkv = (short*)(ws + 23068672);       // 48 MB: q | k | vT
  short* Pp  = (short*)(ws + 73400320);       // 32 MB: [4][2048][2048] bf16
  float* rs  = (float*)(ws + 106954752);      // 32 KB: [4][2048] fp32
  short* vT  = qkv + 2L * 8388608;            // [4][1024][2048] bf16

  // 1. prep: xb, wt, rowsum=0
  k_prep<<<11265, 256, 0, stream>>>((const float4*)x, (ushort4*)xb,
                                    Wq, Wk, Wv, wt, rs);
  // 2. q,k = x@W+b (bf16); v written transposed into vT
  k_qkv<<<1536, 256, 0, stream>>>(xb, wt, qkv, vT, bq, bk, bv);
  // 3. P' = exp2(q@k^T * scale*log2e), bf16 + rowsum atomics  [8-phase 256^2]
  k_score<<<256, 512, 0, stream>>>(qkv, qkv + 8388608, Pp,
                                   0.03125f * 1.44269504088896f, rs);
  // 4. out = (P' @ vT^T) / rowsum  (fp32 -> d_out)
  k_pv<<<512, 256, 0, stream>>>(Pp, vT, (float*)d_out, rs);
}

// Round 2
// 240.212 us; speedup vs baseline: 1.0416x; 1.0392x over previous
//
#include <hip/hip_runtime.h>
#include <hip/hip_bf16.h>
#include <stdint.h>

// ---------------------------------------------------------------------------
// Single-head self-attention, B=4, S=2048, D=1024, fp32 in/out.
// Round 10: NEW k_qkv — 8-phase engine (same as round-9 k_score, which
// verified correct) at 256x128 tiles: 32x24 = 768 blocks = exactly 3 full
// rounds at 1 block/CU (fixes the 75% packing that parked qkv in round 9).
// 512 thr (8 waves of 64x64), BK=64, 96KB dbuf LDS, row-XOR swizzle,
// counted vmcnt(4), setprio. XCD map: each XCD owns 4 M-slabs x 24 N-tiles.
// k_score (round-9 8-phase), k_pv, k_prep unchanged.
// Pipeline (4 dispatches):
//   1. k_prep:  xb=bf16(x); wt=bf16(W^T); rowsum=0
//   2. k_qkv:   q,k = x@W+b (bf16); v -> vT transposed  [8-phase 256x128]
//   3. k_score: P' = exp2(q@k^T*s*log2e) (bf16) + rowsum atomics [8-phase]
//   4. k_pv:    out = (P' @ vT^T)/rowsum (fp32 -> d_out)
// ---------------------------------------------------------------------------

typedef __attribute__((ext_vector_type(8))) short short8;   // 8 bf16 = 4 VGPR
typedef __attribute__((ext_vector_type(4))) float f32x4;    // MFMA C/D

__device__ __forceinline__ unsigned short f2bf(float f) {
  union { float f; uint32_t u; } c; c.f = f;
  uint32_t u = c.u;
  u += 0x7FFFu + ((u >> 16) & 1u);   // RNE
  return (unsigned short)(u >> 16);
}

// async global->LDS, 16B/lane; LDS dest is wave-uniform base + lane*16.
__device__ __forceinline__ void gl16(const void* g, void* l) {
  __builtin_amdgcn_global_load_lds(
      (const __attribute__((address_space(1))) unsigned int*)g,
      (__attribute__((address_space(3))) unsigned int*)l, 16, 0, 0);
}

#define FENCE() asm volatile("" ::: "memory")
#define BARRIER() do { FENCE(); __builtin_amdgcn_s_barrier(); FENCE(); } while (0)
#define VMWAIT(n) asm volatile("s_waitcnt vmcnt(" #n ")" ::: "memory")

// ---------------- k_qkv: 256x128 tile, 512 thr, 8-phase pipeline -----------
// q,k,v = x@W+b. M=8192 (4x2048 tokens), N=3x1024, K=1024.
// 768 blocks = 32 tm x 24 tn(=3z x 8), exactly 3 rounds at 1 block/CU.
// LDS 96KB: 2 bufs x (A 256x64 | B 128x64) bf16, 16B chunks XOR-swizzled
// (slot ^= row&7) so ds_read_b128 fragment reads are conflict-free per
// 8-lane service group. Per K-tile t: P0 {read af(8)+bf0(4), stage B(t+1)},
// P1 {read bf1(4), stage A(t+2)}; vmcnt(4) at tile boundary keeps A(t+2)
// in flight. z==2 tile writes v transposed into vT (per-wave LDS scratch).
__global__ __launch_bounds__(512, 2) void k_qkv(
    const short* __restrict__ A, const short* __restrict__ B,
    short* __restrict__ Cb, short* __restrict__ vT,
    const float* __restrict__ b0, const float* __restrict__ b1,
    const float* __restrict__ b2)
{
  __shared__ short lds[49152];   // 96 KB

  const int b = blockIdx.x;          // 768
  const int xcd = b & 7, r = b >> 3; // r 0..95
  const int tm = xcd * 4 + r / 24;   // 0..31 (each XCD: 4 consecutive slabs)
  const int tn_all = r % 24;         // 0..23
  const int z = tn_all >> 3, tn = tn_all & 7;

  const int tid = threadIdx.x;
  const int lane = tid & 63;
  const int wid = tid >> 6;               // 0..7
  const int fr = lane & 15, quad = lane >> 4, frk = fr & 7;
  const int wm = wid >> 1, wn = wid & 1;  // wave: rows wm*64.., cols wn*64..

  const long tileM = (long)tm * 256;
  const long tileN = (long)tn * 128;
  const short* Az = A;
  const short* Bz = B + (long)z * 1048576L;

  // staging: chunk c -> (row=c>>3, slot=(c&7)^(row&7)); +64-row strides keep
  // the same slot ((row+64)&7 == row&7).
  const int srow = tid >> 3;
  const int sslot = (tid & 7) ^ (srow & 7);
  const short* gA = Az + (tileM + srow) * 1024 + sslot * 8;
  const short* gB = Bz + (tileN + srow) * 1024 + sslot * 8;

  // fragment read offsets (shorts); row&7 == fr&7 (row blocks are x16)
  const int aBase = wm << 12;             // wm*64 rows * 64 shorts
  const int bBase = 16384 + (wn << 12);   // B region + wn*64 rows
  const int o0 = ((quad ^ frk) << 3) + (fr << 6);        // kk=0 slot
  const int o1 = (((quad + 4) ^ frk) << 3) + (fr << 6);  // kk=1 slot

  f32x4 acc[4][4] = {};

  auto stageA = [&](int tt) {          // 4 loads: 256 rows of A tile tt
    const short* s = gA + tt * 64;
    short* d = &lds[(tt & 1) * 24576];
    gl16(s,          d + (tid << 3));
    gl16(s + 65536,  d + 4096 + (tid << 3));
    gl16(s + 131072, d + 8192 + (tid << 3));
    gl16(s + 196608, d + 12288 + (tid << 3));
  };
  auto stageB = [&](int tt) {          // 2 loads: 128 rows of B tile tt
    const short* s = gB + tt * 64;
    short* d = &lds[(tt & 1) * 24576 + 16384];
    gl16(s,         d + (tid << 3));
    gl16(s + 65536, d + 4096 + (tid << 3));
  };

  // prologue: A0(4) B0(2) A1(4); drain A0+B0, keep A1 in flight
  stageA(0); stageB(0); stageA(1);
  VMWAIT(4);
  BARRIER();

#pragma unroll 1
  for (int t = 0; t < 16; ++t) {
    const int bb = (t & 1) * 24576;
    short8 af[4][2], bf0[2][2], bf1[2][2];

    // ---- phase 0: all rows x cols 0-31 (of wave tile)
#pragma unroll
    for (int i = 0; i < 4; ++i) {
      af[i][0] = *(const short8*)&lds[bb + aBase + (i << 10) + o0];
      af[i][1] = *(const short8*)&lds[bb + aBase + (i << 10) + o1];
    }
#pragma unroll
    for (int j = 0; j < 2; ++j) {
      bf0[j][0] = *(const short8*)&lds[bb + bBase + (j << 10) + o0];
      bf0[j][1] = *(const short8*)&lds[bb + bBase + (j << 10) + o1];
    }
    if (t + 1 < 16) stageB(t + 1);
    BARRIER();
    __builtin_amdgcn_s_setprio(1);
#pragma unroll
    for (int i = 0; i < 4; ++i)
#pragma unroll
      for (int j = 0; j < 2; ++j) {
        acc[i][j] = __builtin_amdgcn_mfma_f32_16x16x32_bf16(af[i][0], bf0[j][0], acc[i][j], 0, 0, 0);
        acc[i][j] = __builtin_amdgcn_mfma_f32_16x16x32_bf16(af[i][1], bf0[j][1], acc[i][j], 0, 0, 0);
      }
    __builtin_amdgcn_s_setprio(0);
    BARRIER();

    // ---- phase 1: all rows x cols 32-63; stage A(t+2) (same buf as t,
    // safe: all A reads of buf t completed before P0's end barrier).
#pragma unroll
    for (int j = 0; j < 2; ++j) {
      bf1[j][0] = *(const short8*)&lds[bb + bBase + ((j + 2) << 10) + o0];
      bf1[j][1] = *(const short8*)&lds[bb + bBase + ((j + 2) << 10) + o1];
    }
    if (t + 2 < 16) stageA(t + 2);
    BARRIER();
    __builtin_amdgcn_s_setprio(1);
#pragma unroll
    for (int i = 0; i < 4; ++i)
#pragma unroll
      for (int j = 0; j < 2; ++j) {
        acc[i][j + 2] = __builtin_amdgcn_mfma_f32_16x16x32_bf16(af[i][0], bf1[j][0], acc[i][j + 2], 0, 0, 0);
        acc[i][j + 2] = __builtin_amdgcn_mfma_f32_16x16x32_bf16(af[i][1], bf1[j][1], acc[i][j + 2], 0, 0, 0);
      }
    __builtin_amdgcn_s_setprio(0);
    // tile boundary: drain A(t+1)+B(t+1), keep A(t+2) (4 loads) in flight.
    if (t < 14) { VMWAIT(4); } else { VMWAIT(0); }
    BARRIER();
  }

  __syncthreads();
  // C/D layout: row=(lane>>4)*4+r, col=lane&15 (m89/m91-verified).
  short* scr = &lds[wid * 4608];   // [64][72] per wave (8x4608=36864 shorts)
  if (z == 2) {
    // v-tile: add bias, write TRANSPOSED scratch [d][t], store vT[b][d][t]
#pragma unroll
    for (int j = 0; j < 4; ++j) {
      const float bv = b2[tileN + wn * 64 + j * 16 + fr];
#pragma unroll
      for (int i = 0; i < 4; ++i)
#pragma unroll
        for (int r = 0; r < 4; ++r)
          scr[(j * 16 + fr) * 72 + i * 16 + quad * 4 + r] =
              (short)f2bf(acc[i][j][r] + bv);
    }
    const int gb = tm >> 3;                       // 256-row tiles: 8 per batch
    const long t0 = (long)(tm & 7) * 256 + wm * 64;
#pragma unroll
    for (int c = 0; c < 8; ++c) {
      const int rr = c * 8 + (lane >> 3);
      const int cc = (lane & 7) * 8;
      short8 v = *(const short8*)&scr[rr * 72 + cc];
      const long gd = tileN + wn * 64 + rr;
      *(short8*)(vT + ((long)gb << 21) + gd * 2048 + t0 + cc) = v;
    }
  } else {
    short* C = Cb + (long)z * 8388608L;
    const float* bias = (z == 0) ? b0 : b1;
#pragma unroll
    for (int j = 0; j < 4; ++j) {
      const float bv = bias[tileN + wn * 64 + j * 16 + fr];
#pragma unroll
      for (int i = 0; i < 4; ++i)
#pragma unroll
        for (int r = 0; r < 4; ++r)
          scr[(i * 16 + quad * 4 + r) * 72 + j * 16 + fr] =
              (short)f2bf(acc[i][j][r] + bv);
    }
#pragma unroll
    for (int c = 0; c < 8; ++c) {
      const int row = c * 8 + (lane >> 3);
      const int col = (lane & 7) * 8;
      short8 v = *(const short8*)&scr[row * 72 + col];
      *(short8*)(C + (tileM + wm * 64 + row) * 1024 + tileN + wn * 64 + col) = v;
    }
  }
}

// ---------------- k_score: 256x256 tile, 512 thr, 8-phase pipeline ---------
// P' = exp2(q@k^T * scale) bf16 + rowsum atomics. K=1024, BK=64.
__global__ __launch_bounds__(512, 2) void k_score(
    const short* __restrict__ A, const short* __restrict__ B,
    short* __restrict__ Pp, float scale, float* __restrict__ rowsum)
{
  __shared__ short lds[65536];   // 128 KB

  const int b = blockIdx.x;
  const int xcd = b & 7, jb = b >> 3;
  const int p = xcd * 4 + (jb >> 3);   // 32 (z,tm) slabs, 4 per XCD
  const int tn = jb & 7;
  const int z = p >> 3, tm = p & 7;

  const int tid = threadIdx.x;
  const int lane = tid & 63;
  const int wid = tid >> 6;            // 0..7
  const int fr = lane & 15, quad = lane >> 4;
  const int wm = wid >> 2, wn = wid & 3;   // wave owns rows wm*128.., cols wn*64..

  const long tileM = (long)tm * 256;
  const long tileN = (long)tn * 256;
  const short* Az = A + (long)z * 2097152L;
  const short* Bz = B + (long)z * 2097152L;

  const int srow = tid >> 3;
  const int sslot = (tid & 7) ^ (srow & 7);
  const short* gA = Az + (tileM + srow) * 1024 + sslot * 8;
  const short* gB = Bz + (tileN + srow) * 1024 + sslot * 8;

  const int frk = fr & 7;
  const int aBase = wm << 13;                                 // own A half
  const int bRow  = 16384 + ((wn >> 1) << 13) + ((wn & 1) << 12); // own B half+64
  const int o0 = ((quad ^ frk) << 3) + (fr << 6);             // kk=0 slot
  const int o1 = (((quad + 4) ^ frk) << 3) + (fr << 6);       // kk=1 slot

  f32x4 acc[8][4] = {};

  auto stageA = [&](int tt) {          // 4 loads: both halves of A tile tt
    const short* s = gA + tt * 64;
    short* d = &lds[(tt & 1) << 15];
    gl16(s,          d + (tid << 3));
    gl16(s + 65536,  d + 4096 + (tid << 3));
    gl16(s + 131072, d + 8192 + (tid << 3));
    gl16(s + 196608, d + 12288 + (tid << 3));
  };
  auto stageBh = [&](int tt, int h) {  // 2 loads: B half h of tile tt
    const short* s = gB + tt * 64 + h * 131072;
    short* d = &lds[((tt & 1) << 15) + 16384 + (h << 13)];
    gl16(s,         d + (tid << 3));
    gl16(s + 65536, d + 4096 + (tid << 3));
  };

  // prologue: A0(4) B0(4) A1(4); drain oldest 8, keep A1 in flight
  stageA(0); stageBh(0, 0); stageBh(0, 1); stageA(1);
  VMWAIT(4);
  BARRIER();

#pragma unroll 1
  for (int t = 0; t < 16; ++t) {
    const int bb = (t & 1) << 15;
    short8 af0[4][2], af1[4][2], bf0[2][2], bf1[2][2];

    // ---- phase 0: quadrant rows 0-63 x cols 0-31 (of wave tile)
#pragma unroll
    for (int i = 0; i < 4; ++i) {
      af0[i][0] = *(const short8*)&lds[bb + aBase + (i << 10) + o0];
      af0[i][1] = *(const short8*)&lds[bb + aBase + (i << 10) + o1];
    }
#pragma unroll
    for (int j = 0; j < 2; ++j) {
      bf0[j][0] = *(const short8*)&lds[bb + bRow + (j << 10) + o0];
      bf0[j][1] = *(const short8*)&lds[bb + bRow + (j << 10) + o1];
    }
    if (t + 1 < 16) stageBh(t + 1, 0);
    BARRIER();
    __builtin_amdgcn_s_setprio(1);
#pragma unroll
    for (int i = 0; i < 4; ++i)
#pragma unroll
      for (int j = 0; j < 2; ++j) {
        acc[i][j] = __builtin_amdgcn_mfma_f32_16x16x32_bf16(af0[i][0], bf0[j][0], acc[i][j], 0, 0, 0);
        acc[i][j] = __builtin_amdgcn_mfma_f32_16x16x32_bf16(af0[i][1], bf0[j][1], acc[i][j], 0, 0, 0);
      }
    __builtin_amdgcn_s_setprio(0);
    BARRIER();

    // ---- phase 1: rows 64-127 x cols 0-31
#pragma unroll
    for (int i = 0; i < 4; ++i) {
      af1[i][0] = *(const short8*)&lds[bb + aBase + ((i + 4) << 10) + o0];
      af1[i][1] = *(const short8*)&lds[bb + aBase + ((i + 4) << 10) + o1];
    }
    if (t + 1 < 16) stageBh(t + 1, 1);
    BARRIER();
    __builtin_amdgcn_s_setprio(1);
#pragma unroll
    for (int i = 0; i < 4; ++i)
#pragma unroll
      for (int j = 0; j < 2; ++j) {
        acc[i + 4][j] = __builtin_amdgcn_mfma_f32_16x16x32_bf16(af1[i][0], bf0[j][0], acc[i + 4][j], 0, 0, 0);
        acc[i + 4][j] = __builtin_amdgcn_mfma_f32_16x16x32_bf16(af1[i][1], bf0[j][1], acc[i + 4][j], 0, 0, 0);
      }
    __builtin_amdgcn_s_setprio(0);
    BARRIER();

    // ---- phase 2: rows 64-127 x cols 32-63
#pragma unroll
    for (int j = 0; j < 2; ++j) {
      bf1[j][0] = *(const short8*)&lds[bb + bRow + ((j + 2) << 10) + o0];
      bf1[j][1] = *(const short8*)&lds[bb + bRow + ((j + 2) << 10) + o1];
    }
    BARRIER();
    __builtin_amdgcn_s_setprio(1);
#pragma unroll
    for (int i = 0; i < 4; ++i)
#pragma unroll
      for (int j = 0; j < 2; ++j) {
        acc[i + 4][j + 2] = __builtin_amdgcn_mfma_f32_16x16x32_bf16(af1[i][0], bf1[j][0], acc[i + 4][j + 2], 0, 0, 0);
        acc[i + 4][j + 2] = __builtin_amdgcn_mfma_f32_16x16x32_bf16(af1[i][1], bf1[j][1], acc[i + 4][j + 2], 0, 0, 0);
      }
    __builtin_amdgcn_s_setprio(0);
    BARRIER();

    // ---- phase 3: rows 0-63 x cols 32-63; stage A(t+2)
    if (t + 2 < 16) stageA(t + 2);
    BARRIER();
    __builtin_amdgcn_s_setprio(1);
#pragma unroll
    for (int i = 0; i < 4; ++i)
#pragma unroll
      for (int j = 0; j < 2; ++j) {
        acc[i][j + 2] = __builtin_amdgcn_mfma_f32_16x16x32_bf16(af0[i][0], bf1[j][0], acc[i][j + 2], 0, 0, 0);
        acc[i][j + 2] = __builtin_amdgcn_mfma_f32_16x16x32_bf16(af0[i][1], bf1[j][1], acc[i][j + 2], 0, 0, 0);
      }
    __builtin_amdgcn_s_setprio(0);
    if (t < 14) { VMWAIT(4); } else { VMWAIT(0); }
    BARRIER();
  }

  // exp2 (register-only)
#pragma unroll
  for (int i = 0; i < 8; ++i)
#pragma unroll
    for (int j = 0; j < 4; ++j)
#pragma unroll
      for (int r = 0; r < 4; ++r)
        acc[i][j][r] = exp2f(acc[i][j][r] * scale);

  // rowsum partials
  float* rsz = rowsum + (long)z * 2048 + tileM + wm * 128;
#pragma unroll
  for (int i = 0; i < 8; ++i)
#pragma unroll
    for (int r = 0; r < 4; ++r) {
      float s = acc[i][0][r] + acc[i][1][r] + acc[i][2][r] + acc[i][3][r];
      s += __shfl_xor(s, 1);
      s += __shfl_xor(s, 2);
      s += __shfl_xor(s, 4);
      s += __shfl_xor(s, 8);
      if (fr == 0) atomicAdd(&rsz[i * 16 + quad * 4 + r], s);
    }

  // bf16 store via per-wave LDS transpose scratch
  __syncthreads();
  short* C = Pp + (long)z * 4194304L;
  short* scr = &lds[wid * 4608];   // [64][72] per wave
#pragma unroll
  for (int pass = 0; pass < 2; ++pass) {
#pragma unroll
    for (int j = 0; j < 4; ++j)
#pragma unroll
      for (int i = 0; i < 4; ++i)
#pragma unroll
        for (int r = 0; r < 4; ++r)
          scr[(i * 16 + quad * 4 + r) * 72 + j * 16 + fr] =
              (short)f2bf(acc[pass * 4 + i][j][r]);
#pragma unroll
    for (int c = 0; c < 8; ++c) {
      const int row = c * 8 + (lane >> 3);
      const int col = (lane & 7) * 8;
      short8 v = *(const short8*)&scr[row * 72 + col];
      *(short8*)(C + (tileM + wm * 128 + pass * 64 + row) * 2048 +
                 tileN + wn * 64 + col) = v;
    }
  }
}

// ----------------- k_pv: 128x128, 256 thr, swizzled (round 4) --------------
// out = (P' @ vT^T) / rowsum, fp32. K=2048, BK=32 dbuf. Grid 512.
__global__ __launch_bounds__(256) void k_pv(
    const short* __restrict__ A, const short* __restrict__ B,
    float* __restrict__ Cf, float* __restrict__ rowsum)
{
  const int b = blockIdx.x;
  const int s = b & 7, r0_ = b >> 3;
  const int z = r0_ >> 4;
  const int mem = r0_ & 15;
  const int tm = (s >> 1) * 4 + (mem >> 2);
  const int tn = (s & 1) * 4 + (mem & 3);

  __shared__ short lds[18432];

  const int tid  = threadIdx.x;
  const int lane = tid & 63;
  const int wid  = tid >> 6;
  const long tileM = (long)tm * 128;
  const long tileN = (long)tn * 128;
  const short* Az = A + (long)z * 4194304L;
  const short* Bz = B + (long)z * 2097152L;

  const int c0 = tid, c1 = 256 + tid;
  const short* gA0 = Az + (tileM + (c0 >> 2)) * 2048 + (c0 & 3) * 8;
  const short* gA1 = Az + (tileM + (c1 >> 2)) * 2048 + (c1 & 3) * 8;
  const short* gB0 = Bz + (tileN + (c0 >> 2)) * 2048 + (c0 & 3) * 8;
  const short* gB1 = Bz + (tileN + (c1 >> 2)) * 2048 + (c1 & 3) * 8;

  const int fr = lane & 15, quad = lane >> 4;
  const int waveM = (wid >> 1) * 64, waveN = (wid & 1) * 64;

  f32x4 acc[4][4] = {};

  {
    short* base = lds;
    gl16(gA0, base + c0 * 8);
    gl16(gA1, base + c1 * 8);
    gl16(gB0, base + 4096 + c0 * 8);
    gl16(gB1, base + 4096 + c1 * 8);
  }

  for (int t = 0; t < 64; ++t) {
    __syncthreads();
    if (t + 1 < 64) {
      const int kt = (t + 1) << 5;
      short* base = lds + ((t + 1) & 1) * 8192;
      gl16(gA0 + kt, base + c0 * 8);
      gl16(gA1 + kt, base + c1 * 8);
      gl16(gB0 + kt, base + 4096 + c0 * 8);
      gl16(gB1 + kt, base + 4096 + c1 * 8);
    }
    const short* sA = lds + (t & 1) * 8192;
    const short* sB = sA + 4096;
    short8 af[4], bf[4];
#pragma unroll
    for (int i = 0; i < 4; ++i)
      af[i] = *(const short8*)&sA[(waveM + i * 16 + fr) * 32 + quad * 8];
#pragma unroll
    for (int j = 0; j < 4; ++j)
      bf[j] = *(const short8*)&sB[(waveN + j * 16 + fr) * 32 + quad * 8];
#pragma unroll
    for (int i = 0; i < 4; ++i)
#pragma unroll
      for (int j = 0; j < 4; ++j)
        acc[i][j] = __builtin_amdgcn_mfma_f32_16x16x32_bf16(af[i], bf[j],
                                                            acc[i][j], 0, 0, 0);
  }

  float* C = Cf + (long)z * 2097152L;
#pragma unroll
  for (int i = 0; i < 4; ++i)
#pragma unroll
    for (int r = 0; r < 4; ++r) {
      const long gr = tileM + waveM + i * 16 + quad * 4 + r;
      const float rinv = 1.0f / rowsum[(long)z * 2048 + gr];
#pragma unroll
      for (int j = 0; j < 4; ++j)
        C[gr * 1024 + tileN + waveN + j * 16 + fr] = acc[i][j][r] * rinv;
    }
}

// prep: blocks [0,8192) cvt x -> bf16; [8192,11264) W^T -> bf16; 11264 zero rs
__global__ __launch_bounds__(256) void k_prep(
    const float4* __restrict__ x, ushort4* __restrict__ xb,
    const float* __restrict__ Wq, const float* __restrict__ Wk,
    const float* __restrict__ Wv, short* __restrict__ WT,
    float* __restrict__ rs)
{
  __shared__ short tile[32][33];
  const int b = blockIdx.x;
  if (b < 8192) {
    const long i = (long)b * 256 + threadIdx.x;
    float4 v = x[i];
    ushort4 o;
    o.x = f2bf(v.x); o.y = f2bf(v.y); o.z = f2bf(v.z); o.w = f2bf(v.w);
    xb[i] = o;
  } else if (b < 11264) {
    const int idx = b - 8192;
    const int z = idx >> 10, rem = idx & 1023;
    const float* W = (z == 0) ? Wq : ((z == 1) ? Wk : Wv);
    short* d = WT + (long)z * 1024 * 1024;
    const int n0 = (rem & 31) * 32, d0 = (rem >> 5) * 32;
    const int tx = threadIdx.x & 31, ty = threadIdx.x >> 5;
#pragma unroll
    for (int p = 0; p < 4; ++p)
      tile[ty + p * 8][tx] = (short)f2bf(W[(long)(d0 + ty + p * 8) * 1024 + n0 + tx]);
    __syncthreads();
#pragma unroll
    for (int p = 0; p < 4; ++p)
      d[(long)(n0 + ty + p * 8) * 1024 + d0 + tx] = tile[tx][ty + p * 8];
  } else {
#pragma unroll
    for (int p = 0; p < 32; ++p)
      rs[p * 256 + threadIdx.x] = 0.0f;
  }
}

extern "C" void kernel_launch(void* const* d_in, const int* in_sizes, int n_in,
                              void* d_out, int out_size, void* d_ws, size_t ws_size,
                              hipStream_t stream) {
  const float* x  = (const float*)d_in[0];
  const float* Wq = (const float*)d_in[1];
  const float* bq = (const float*)d_in[2];
  const float* Wk = (const float*)d_in[3];
  const float* bk = (const float*)d_in[4];
  const float* Wv = (const float*)d_in[5];
  const float* bv = (const float*)d_in[6];

  char* ws = (char*)d_ws;
  short* xb  = (short*)(ws);                  // 16 MB
  short* wt  = (short*)(ws + 16777216);       // 6 MB
  short* qkv = (short*)(ws + 23068672);       // 48 MB: q | k | vT
  short* Pp  = (short*)(ws + 73400320);       // 32 MB: [4][2048][2048] bf16
  float* rs  = (float*)(ws + 106954752);      // 32 KB: [4][2048] fp32
  short* vT  = qkv + 2L * 8388608;            // [4][1024][2048] bf16

  // 1. prep: xb, wt, rowsum=0
  k_prep<<<11265, 256, 0, stream>>>((const float4*)x, (ushort4*)xb,
                                    Wq, Wk, Wv, wt, rs);
  // 2. q,k = x@W+b (bf16); v written transposed into vT  [8-phase 256x128]
  k_qkv<<<768, 512, 0, stream>>>(xb, wt, qkv, vT, bq, bk, bv);
  // 3. P' = exp2(q@k^T * scale*log2e), bf16 + rowsum atomics  [8-phase 256^2]
  k_score<<<256, 512, 0, stream>>>(qkv, qkv + 8388608, Pp,
                                   0.03125f * 1.44269504088896f, rs);
  // 4. out = (P' @ vT^T) / rowsum  (fp32 -> d_out)
  k_pv<<<512, 256, 0, stream>>>(Pp, vT, (float*)d_out, rs);
}